// Round 3
// baseline (1017.256 us; speedup 1.0000x reference)
//
#include <hip/hip_runtime.h>
#include <hip/hip_bf16.h>
#include <math.h>

// Problem dims
#define B_   32
#define NO_  100
#define NE_  600
#define NK_  1000
#define KE_  1000
#define L_   8
#define R_   8
#define H_   512
#define IMG_ 2048
#define LOC_ 5
#define EMB_ 300
#define MID_ 512
#define C_   3000
#define PAD_ 1

#define NN_  (NO_ + NK_)   // 1100 node keys
#define NEK_ (NE_ + KE_)   // 1600 edge keys

typedef __attribute__((ext_vector_type(8))) short bf16x8;
typedef __attribute__((ext_vector_type(4))) float f32x4;

__device__ __forceinline__ float4 ldf4(const float* p) { return *(const float4*)p; }

__device__ __forceinline__ float bf2f(short s) {
    unsigned u = ((unsigned)(unsigned short)s) << 16;
    float f; __builtin_memcpy(&f, &u, 4); return f;
}
__device__ __forceinline__ short f2bf(float f) {
    unsigned u; __builtin_memcpy(&u, &f, 4);
    u = (u + 0x7fffu + ((u >> 16) & 1u)) >> 16;   // round-nearest-even
    return (short)u;
}

// ---------------------------------------------------------------------------
// W_prep: f32 W[K][512] -> bf16 tiles [NB=4][KS][4 kg][128 nl][8 j]
// entry = W[ks*32+kg*8+j][nb*128+nl]  (zeros for k >= K)
__global__ __launch_bounds__(256) void wprep_kernel(
    const float* __restrict__ W, short* __restrict__ Wp, int K, int KS)
{
    int idx = blockIdx.x * 256 + threadIdx.x;
    int total = 4 * KS * 4 * 128;
    if (idx >= total) return;
    int nl = idx & 127;
    int kg = (idx >> 7) & 3;
    int t  = idx >> 9;            // nb*KS + ks
    int ks = t % KS;
    int nb = t / KS;
    int n = nb * 128 + nl;
    short o[8];
#pragma unroll
    for (int j = 0; j < 8; ++j) {
        int k = ks * 32 + kg * 8 + j;
        o[j] = (k < K) ? f2bf(W[(long)k * H_ + n]) : (short)0;
    }
    *(uint4*)&Wp[(long)idx * 8] = *(uint4*)o;
}

// f32 -> bf16 elementwise (n multiple of 8)
__global__ __launch_bounds__(256) void cvt_bf16_kernel(
    const float* __restrict__ src, short* __restrict__ dst, long n)
{
    long i = ((long)blockIdx.x * 256 + threadIdx.x) * 8;
    if (i >= n) return;
    float4 a = ldf4(src + i), b = ldf4(src + i + 4);
    short o[8] = { f2bf(a.x), f2bf(a.y), f2bf(a.z), f2bf(a.w),
                   f2bf(b.x), f2bf(b.y), f2bf(b.z), f2bf(b.w) };
    *(uint4*)&dst[i] = *(uint4*)o;
}

// ---------------------------------------------------------------------------
// MFMA GEMM: 128x128 tile, BK=32, 4 waves each owning 64x64.
// A: bf16 row-major (AV=0) or gathered img_f rows (AV=2, K=1024 two halves).
// B: W_prep tiles (linear copy to LDS).
// EP: 0 img_node (img_f + node_keys w/ loc), 1 img_edge, 2 score partials.
template<int AV, int EP>
__global__ __launch_bounds__(256) void mfma_gemm_kernel(
    const short* __restrict__ A, int lda, const short* __restrict__ Wp, int KS,
    const int* __restrict__ id1, const int* __restrict__ id2,
    const short* __restrict__ Agather,
    const float* __restrict__ bias, const float* __restrict__ bias2,
    const float* __restrict__ loc, const float* __restrict__ Wloc,
    const float* __restrict__ qp, const float* __restrict__ vvec,
    short* __restrict__ out0, short* __restrict__ out1,
    float* __restrict__ sout, int Nrows, int Mtot)
{
    __shared__ __align__(16) short As[4096];   // [4 kg][128 r][8]
    __shared__ __align__(16) short Bs[4096];   // [4 kg][128 n][8]
    int tid = threadIdx.x;
    int m0 = blockIdx.x * 128, nb = blockIdx.y, n0 = nb * 128;
    int w = tid >> 6, l = tid & 63, wr = w >> 1, wc = w & 1;
    int sr = tid >> 1, sh = tid & 1;

    long arow_off = 0; int r1 = 0, r2 = 0;
    if (AV == 0) {
        arow_off = (long)(m0 + sr) * lda;
    } else {
        int i = m0 + sr;
        int b = i / NE_;
        r1 = b * NO_ + id1[i];
        r2 = b * NO_ + id2[i];
    }
    const short* wslab = Wp + (long)nb * KS * 4096;

    uint4 av0, av1, bv0, bv1;
    auto loadA = [&](int ks) {
        const short* p;
        if (AV == 0) p = A + arow_off + ks * 32 + sh * 16;
        else {
            int kk = ks * 32;
            int row = (kk < 512) ? r1 : r2;
            p = Agather + (long)row * 512 + (kk & 511) + sh * 16;
        }
        av0 = *(const uint4*)p;
        av1 = *(const uint4*)(p + 8);
    };
    auto loadB = [&](int ks) {
        const uint4* p = (const uint4*)(wslab + (long)ks * 4096 + tid * 16);
        bv0 = p[0]; bv1 = p[1];
    };

    f32x4 acc[4][4];
#pragma unroll
    for (int m = 0; m < 4; ++m)
#pragma unroll
        for (int n = 0; n < 4; ++n)
#pragma unroll
            for (int k = 0; k < 4; ++k) acc[m][n][k] = 0.f;

    int kg = l >> 4, li = l & 15;
    loadA(0); loadB(0);
    for (int ks = 0; ks < KS; ++ks) {
        __syncthreads();                       // prior reads done
        *(uint4*)&As[(sh * 2) * 1024 + sr * 8]     = av0;
        *(uint4*)&As[(sh * 2 + 1) * 1024 + sr * 8] = av1;
        *(uint4*)&Bs[tid * 16]     = bv0;
        *(uint4*)&Bs[tid * 16 + 8] = bv1;
        __syncthreads();
        if (ks + 1 < KS) { loadA(ks + 1); loadB(ks + 1); }  // prefetch under MFMA
        bf16x8 af[4], bfr[4];
#pragma unroll
        for (int m = 0; m < 4; ++m)
            af[m] = *(const bf16x8*)&As[kg * 1024 + (wr * 64 + m * 16 + li) * 8];
#pragma unroll
        for (int n = 0; n < 4; ++n)
            bfr[n] = *(const bf16x8*)&Bs[kg * 1024 + (wc * 64 + n * 16 + li) * 8];
#pragma unroll
        for (int m = 0; m < 4; ++m)
#pragma unroll
            for (int n = 0; n < 4; ++n)
                acc[m][n] = __builtin_amdgcn_mfma_f32_16x16x32_bf16(af[m], bfr[n], acc[m][n], 0, 0, 0);
    }

    int jrow4 = (l >> 4) * 4;
    if (EP == 0) {                             // img_node
        float bi[4], bl[4], wl[4][5];
#pragma unroll
        for (int n = 0; n < 4; ++n) {
            int col = n0 + wc * 64 + n * 16 + li;
            bi[n] = bias[col]; bl[n] = bias2[col];
#pragma unroll
            for (int j5 = 0; j5 < 5; ++j5) wl[n][j5] = Wloc[j5 * H_ + col];
        }
#pragma unroll
        for (int m = 0; m < 4; ++m)
#pragma unroll
            for (int j = 0; j < 4; ++j) {
                int row = m0 + wr * 64 + m * 16 + jrow4 + j;
                int b = row / NO_, o = row - b * NO_;
                float lv[5];
#pragma unroll
                for (int j5 = 0; j5 < 5; ++j5) lv[j5] = loc[(long)row * 5 + j5];
#pragma unroll
                for (int n = 0; n < 4; ++n) {
                    int col = n0 + wc * 64 + n * 16 + li;
                    float val = acc[m][n][j] + bi[n];
                    out0[(long)row * H_ + col] = f2bf(val);
                    float nk = val + bl[n];
#pragma unroll
                    for (int j5 = 0; j5 < 5; ++j5) nk = fmaf(lv[j5], wl[n][j5], nk);
                    out1[((long)b * NN_ + o) * H_ + col] = f2bf(nk);
                }
            }
    } else if (EP == 1) {                      // img_edge
        float bi[4];
#pragma unroll
        for (int n = 0; n < 4; ++n) bi[n] = bias[n0 + wc * 64 + n * 16 + li];
#pragma unroll
        for (int m = 0; m < 4; ++m)
#pragma unroll
            for (int j = 0; j < 4; ++j) {
                int row = m0 + wr * 64 + m * 16 + jrow4 + j;
                int b = row / NE_, e = row - b * NE_;
#pragma unroll
                for (int n = 0; n < 4; ++n) {
                    int col = n0 + wc * 64 + n * 16 + li;
                    out0[((long)b * NEK_ + e) * H_ + col] = f2bf(acc[m][n][j] + bi[n]);
                }
            }
    } else {                                   // score partials
        float vv[4];
        int cols[4];
#pragma unroll
        for (int n = 0; n < 4; ++n) {
            cols[n] = n0 + wc * 64 + n * 16 + li;
            vv[n] = vvec[cols[n]];
        }
        int slot = nb * 2 + wc;
#pragma unroll
        for (int m = 0; m < 4; ++m)
#pragma unroll
            for (int j = 0; j < 4; ++j) {
                int row = m0 + wr * 64 + m * 16 + jrow4 + j;
                int b = row / Nrows;
                const float* qpb = qp + (long)b * H_;
                float p = 0.f;
#pragma unroll
                for (int n = 0; n < 4; ++n)
                    p += tanhf(qpb[cols[n]] + acc[m][n][j]) * vv[n];
                p += __shfl_xor(p, 1); p += __shfl_xor(p, 2);
                p += __shfl_xor(p, 4); p += __shfl_xor(p, 8);
                if (li == 0) sout[(long)slot * Mtot + row] = p;
            }
    }
}

// ---------------------------------------------------------------------------
// lang_encode with MFMA: 32 rows/block; pooled bf16 in LDS [40 kg][32 r][8];
// W_lang prep [4 nb][10 ks][4096]; 4 waves each own 128 cols.
template<int OUTF32>
__global__ __launch_bounds__(256) void lang_mfma_kernel(
    const int* __restrict__ tokens, int tok_stride, int tok_off,
    const float* __restrict__ embed, const short* __restrict__ Wp,
    const float* __restrict__ bias,
    void* __restrict__ out, int rows_per_b, long out_bstride, long out_roff,
    float* __restrict__ maskout, int nrows)
{
    __shared__ int   toks[32][8];
    __shared__ float rinv[32];
    __shared__ __align__(16) short Ap[40 * 32 * 8];   // 20 KB
    __shared__ __align__(16) short Bs[4 * 4096];      // 32 KB
    int tid = threadIdx.x;
    int base = blockIdx.x * 32;
    {
        int r = tid >> 3, tt = tid & 7;
        toks[r][tt] = tokens[tok_off + (long)(base + r) * tok_stride + tt];
    }
    __syncthreads();
    if (tid < 32) {
        int c = 0;
#pragma unroll
        for (int t = 0; t < 8; ++t) c += (toks[tid][t] != PAD_);
        rinv[tid] = 1.f / fmaxf((float)c, 1.f);
        if (maskout) maskout[base + tid] = (c > 0) ? 1.f : 0.f;
    }
    __syncthreads();

    for (int task = tid; task < 1280; task += 256) {
        int r = task / 40, kg = task - r * 40;
        float s[8] = {0.f,0.f,0.f,0.f,0.f,0.f,0.f,0.f};
        if (kg <= 37) {
#pragma unroll
            for (int t = 0; t < 8; ++t) {
                int tok = toks[r][t];
                if (tok != PAD_) {
                    const float* ep = embed + (long)tok * EMB_ + kg * 8;
                    float4 a = ldf4(ep);
                    s[0] += a.x; s[1] += a.y; s[2] += a.z; s[3] += a.w;
                    if (kg < 37) {
                        float4 b = ldf4(ep + 4);
                        s[4] += b.x; s[5] += b.y; s[6] += b.z; s[7] += b.w;
                    }
                }
            }
        }
        float iv = rinv[r];
        short o[8];
#pragma unroll
        for (int j = 0; j < 8; ++j) o[j] = f2bf(s[j] * iv);
        *(uint4*)&Ap[(kg * 32 + r) * 8] = *(uint4*)o;
    }

    int w = tid >> 6, l = tid & 63, kg = l >> 4, li = l & 15;
    f32x4 acc[2][8];
#pragma unroll
    for (int m = 0; m < 2; ++m)
#pragma unroll
        for (int n = 0; n < 8; ++n)
#pragma unroll
            for (int k = 0; k < 4; ++k) acc[m][n][k] = 0.f;

    for (int ks = 0; ks < 10; ++ks) {
        __syncthreads();
#pragma unroll
        for (int c = 0; c < 4; ++c) {
            int flat = c * 256 + tid;       // 1024 x 32B
            int nb = flat >> 8, rest = flat & 255;
            const uint4* p = (const uint4*)(Wp + (long)(nb * 10 + ks) * 4096 + rest * 16);
            uint4* q = (uint4*)&Bs[nb * 4096 + rest * 16];
            q[0] = p[0]; q[1] = p[1];
        }
        __syncthreads();
        bf16x8 af[2];
#pragma unroll
        for (int m = 0; m < 2; ++m)
            af[m] = *(const bf16x8*)&Ap[((ks * 4 + kg) * 32 + m * 16 + li) * 8];
#pragma unroll
        for (int n = 0; n < 8; ++n) {
            bf16x8 bf = *(const bf16x8*)&Bs[w * 4096 + kg * 1024 + (n * 16 + li) * 8];
#pragma unroll
            for (int m = 0; m < 2; ++m)
                acc[m][n] = __builtin_amdgcn_mfma_f32_16x16x32_bf16(af[m], bf, acc[m][n], 0, 0, 0);
        }
    }

#pragma unroll
    for (int m = 0; m < 2; ++m)
#pragma unroll
        for (int j = 0; j < 4; ++j) {
            int r = m * 16 + (l >> 4) * 4 + j;
            int i = base + r;
            if (i >= nrows) continue;
            int b = i / rows_per_b, k = i - b * rows_per_b;
#pragma unroll
            for (int n = 0; n < 8; ++n) {
                int col = w * 128 + n * 16 + li;
                float val = tanhf(acc[m][n][j] + bias[col]);
                long idx = (long)b * out_bstride + out_roff + (long)k * H_ + col;
                if (OUTF32) ((float*)out)[idx] = val;
                else        ((short*)out)[idx] = f2bf(val);
            }
        }
}

// ---------------------------------------------------------------------------
// Softmax weights: combine 8 deterministic partials, mask, softmax-normalize.
// grid (B, 2): y==0 node set, y==1 edge set.
__global__ __launch_bounds__(256) void softmax_w_kernel(
    const float* __restrict__ sp_n, const float* __restrict__ sp_e,
    const float* __restrict__ maskbuf, float* __restrict__ wn, float* __restrict__ we)
{
    __shared__ float sw[NEK_];
    __shared__ float red[256];
    int b = blockIdx.x, tid = threadIdx.x, set = blockIdx.y;
    const float* sp = set ? sp_e : sp_n;
    float* wout = set ? we : wn;
    int N = set ? NEK_ : NN_;
    long Mtot = set ? (long)B_ * NEK_ : (long)B_ * NN_;

    float lmax = -3.0e38f;
    for (int n = tid; n < N; n += 256) {
        long row = (long)b * N + n;
        float x = 0.f;
#pragma unroll
        for (int s = 0; s < 8; ++s) x += sp[(long)s * Mtot + row];
        if (!set && n >= NO_ && maskbuf[(long)b * NK_ + (n - NO_)] == 0.f) x = -1e30f;
        sw[n] = x;
        lmax = fmaxf(lmax, x);
    }
    red[tid] = lmax; __syncthreads();
    for (int st = 128; st > 0; st >>= 1) {
        if (tid < st) red[tid] = fmaxf(red[tid], red[tid + st]);
        __syncthreads();
    }
    float mx = red[0]; __syncthreads();

    float lsum = 0.f;
    for (int n = tid; n < N; n += 256) {
        float e = expf(sw[n] - mx);
        sw[n] = e;
        lsum += e;
    }
    red[tid] = lsum; __syncthreads();
    for (int st = 128; st > 0; st >>= 1) {
        if (tid < st) red[tid] += red[tid + st];
        __syncthreads();
    }
    float invZ = 1.0f / red[0];
    __syncthreads();
    for (int n = tid; n < N; n += 256)
        wout[(long)b * N + n] = sw[n] * invZ;
}

// ---------------------------------------------------------------------------
// Weighted key sum, split over n: grid (B, SP). Thread: 8 cols x N/SP/4 rows.
// Deterministic partials [SP][B][512].
template<int SP>
__global__ __launch_bounds__(256) void wsum_kernel(
    const float* __restrict__ w, const short* __restrict__ keys,
    float* __restrict__ partial, int N)
{
    __shared__ float red[4][512];
    int b = blockIdx.x, sp = blockIdx.y, tid = threadIdx.x;
    int c8 = (tid & 63) * 8, rsub = tid >> 6;
    int per = (N + SP - 1) / SP;
    int n0 = sp * per, n1 = min(n0 + per, N);
    float acc[8] = {0.f,0.f,0.f,0.f,0.f,0.f,0.f,0.f};
    for (int n = n0 + rsub; n < n1; n += 4) {
        float wv = w[(long)b * N + n];
        bf16x8 k = *(const bf16x8*)&keys[((long)b * N + n) * H_ + c8];
#pragma unroll
        for (int j = 0; j < 8; ++j) acc[j] = fmaf(wv, bf2f(k[j]), acc[j]);
    }
    *(float4*)&red[rsub][c8]     = *(float4*)acc;
    *(float4*)&red[rsub][c8 + 4] = *(float4*)(acc + 4);
    __syncthreads();
    if (rsub == 0) {
        float o[8];
#pragma unroll
        for (int j = 0; j < 8; ++j)
            o[j] = red[0][c8 + j] + red[1][c8 + j] + red[2][c8 + j] + red[3][c8 + j];
        float* op = &partial[((long)sp * B_ + b) * H_ + c8];
        *(float4*)op       = *(float4*)o;
        *(float4*)(op + 4) = *(float4*)(o + 4);
    }
}

// fin = sum over 16 node partials + 16 edge partials. grid (B*H/256).
__global__ __launch_bounds__(256) void fin_reduce_kernel(
    const float* __restrict__ pn, const float* __restrict__ pe, float* __restrict__ fin)
{
    int i = blockIdx.x * 256 + threadIdx.x;
    float s = 0.f;
#pragma unroll
    for (int sp = 0; sp < 16; ++sp)
        s += pn[(long)sp * B_ * H_ + i] + pe[(long)sp * B_ * H_ + i];
    fin[i] = s;
}

// ---------------------------------------------------------------------------
// Batched matvec: BGRP batch rows share one weight read.
// grid (B/BGRP, ceil(C/256)). out[b,c] = act(in[b,:] @ W + bias)
template<int ACT, int BGRP>
__global__ __launch_bounds__(256) void bmatvec_g_kernel(
    const float* __restrict__ in, const float* __restrict__ W,
    const float* __restrict__ bias, float* __restrict__ outp, int E, int C)
{
    __shared__ float ins[BGRP][512];
    int bg = blockIdx.x * BGRP, tid = threadIdx.x;
    for (int t = tid; t < BGRP * E; t += 256) {
        int g = t / 512, e = t & 511;
        if (e < E) ins[g][e] = in[(long)(bg + g) * E + e];
    }
    __syncthreads();
    int c = blockIdx.y * 256 + tid;
    if (c >= C) return;
    float base = bias ? bias[c] : 0.0f;
    float acc[BGRP];
#pragma unroll
    for (int g = 0; g < BGRP; ++g) acc[g] = base;
#pragma unroll 4
    for (int e = 0; e < E; ++e) {
        float wv = W[(long)e * C + c];
#pragma unroll
        for (int g = 0; g < BGRP; ++g) acc[g] = fmaf(ins[g][e], wv, acc[g]);
    }
#pragma unroll
    for (int g = 0; g < BGRP; ++g) {
        float v = (ACT == 1) ? tanhf(acc[g]) : acc[g];
        outp[(long)(bg + g) * C + c] = v;
    }
}

// ---------------------------------------------------------------------------
extern "C" void kernel_launch(void* const* d_in, const int* in_sizes, int n_in,
                              void* d_out, int out_size, void* d_ws, size_t ws_size,
                              hipStream_t stream)
{
    (void)in_sizes; (void)n_in; (void)out_size; (void)ws_size;

    const float* img_feat  = (const float*)d_in[0];
    const float* img_loc   = (const float*)d_in[1];
    const int*   id1       = (const int*)d_in[2];
    const int*   id2       = (const int*)d_in[3];
    const int*   kg_entity = (const int*)d_in[4];
    const int*   kg_edge   = (const int*)d_in[7];
    const int*   r_nodes   = (const int*)d_in[8];
    const float* embed     = (const float*)d_in[11];
    const float* W_lang    = (const float*)d_in[12];
    const float* b_lang    = (const float*)d_in[13];
    const float* W_img     = (const float*)d_in[14];
    const float* b_img     = (const float*)d_in[15];
    const float* W_loc     = (const float*)d_in[16];
    const float* b_loc     = (const float*)d_in[17];
    const float* W_rel     = (const float*)d_in[18];
    const float* b_rel     = (const float*)d_in[19];
    const float* Wq_n      = (const float*)d_in[20];
    const float* Wk_n      = (const float*)d_in[21];
    const float* v_n       = (const float*)d_in[22];
    const float* Wq_e      = (const float*)d_in[23];
    const float* Wk_e      = (const float*)d_in[24];
    const float* v_e       = (const float*)d_in[25];
    const float* W1        = (const float*)d_in[26];
    const float* b1        = (const float*)d_in[27];
    const float* W2        = (const float*)d_in[28];
    const float* b2        = (const float*)d_in[29];
    float* out = (float*)d_out;

    char* ws = (char*)d_ws;
    size_t off = 0;
    auto allocS = [&](size_t n) { short* p = (short*)(ws + off); off += ((n * 2 + 255) & ~255ULL); return p; };
    auto allocF = [&](size_t n) { float* p = (float*)(ws + off); off += ((n * 4 + 255) & ~255ULL); return p; };

    short* img_feat_bf = allocS((size_t)B_ * NO_ * IMG_);      // 13 MB
    short* Wp_img      = allocS((size_t)4 * 64 * 4096);
    short* Wp_rel      = allocS((size_t)4 * 32 * 4096);
    short* Wp_kn       = allocS((size_t)4 * 16 * 4096);
    short* Wp_ke       = allocS((size_t)4 * 16 * 4096);
    short* Wp_lang     = allocS((size_t)4 * 10 * 4096);
    short* img_f_bf    = allocS((size_t)B_ * NO_ * H_);
    short* node_keys   = allocS((size_t)B_ * NN_ * H_);        // 36 MB
    short* edge_keys   = allocS((size_t)B_ * NEK_ * H_);       // 52 MB
    float* rfeat   = allocF((size_t)B_ * H_);
    float* qp_n    = allocF((size_t)B_ * H_);
    float* qp_e    = allocF((size_t)B_ * H_);
    float* mask_kg = allocF((size_t)B_ * NK_);
    float* sp_n    = allocF((size_t)8 * B_ * NN_);             // score partials
    float* sp_e    = allocF((size_t)8 * B_ * NEK_);
    float* wn      = allocF((size_t)B_ * NN_);                 // softmax weights
    float* we      = allocF((size_t)B_ * NEK_);
    float* pn      = allocF((size_t)16 * B_ * H_);             // wsum partials
    float* pe      = allocF((size_t)16 * B_ * H_);
    float* fin     = allocF((size_t)B_ * H_);
    float* hid     = allocF((size_t)B_ * H_);

    // --- weight prep + input conversion ---
    cvt_bf16_kernel<<<(B_ * NO_ * IMG_ / 8 + 255) / 256, 256, 0, stream>>>(
        img_feat, img_feat_bf, (long)B_ * NO_ * IMG_);
    wprep_kernel<<<512, 256, 0, stream>>>(W_img,  Wp_img,  IMG_, 64);
    wprep_kernel<<<256, 256, 0, stream>>>(W_rel,  Wp_rel,  1024, 32);
    wprep_kernel<<<128, 256, 0, stream>>>(Wk_n,   Wp_kn,   512,  16);
    wprep_kernel<<<128, 256, 0, stream>>>(Wk_e,   Wp_ke,   512,  16);
    wprep_kernel<<< 80, 256, 0, stream>>>(W_lang, Wp_lang, EMB_, 10);

    // --- language encodes ---
    lang_mfma_kernel<1><<<1, 256, 0, stream>>>(
        r_nodes, R_ * L_, (R_ - 1) * L_, embed, Wp_lang, b_lang,
        rfeat, 1, (long)H_, 0L, nullptr, B_);
    lang_mfma_kernel<0><<<B_ * NK_ / 32, 256, 0, stream>>>(
        kg_entity, L_, 0, embed, Wp_lang, b_lang,
        node_keys, NK_, (long)NN_ * H_, (long)NO_ * H_, mask_kg, B_ * NK_);
    lang_mfma_kernel<0><<<B_ * KE_ / 32, 256, 0, stream>>>(
        kg_edge, L_, 0, embed, Wp_lang, b_lang,
        edge_keys, KE_, (long)NEK_ * H_, (long)NE_ * H_, nullptr, B_ * KE_);

    // --- qp for root program node ---
    bmatvec_g_kernel<0, 8><<<dim3(B_ / 8, 2), 256, 0, stream>>>(rfeat, Wq_n, nullptr, qp_n, H_, MID_);
    bmatvec_g_kernel<0, 8><<<dim3(B_ / 8, 2), 256, 0, stream>>>(rfeat, Wq_e, nullptr, qp_e, H_, MID_);

    // --- image branches ---
    mfma_gemm_kernel<0, 0><<<dim3(B_ * NO_ / 128, 4), 256, 0, stream>>>(
        img_feat_bf, IMG_, Wp_img, 64, nullptr, nullptr, nullptr,
        b_img, b_loc, img_loc, W_loc, nullptr, nullptr,
        img_f_bf, node_keys, nullptr, 0, 0);
    mfma_gemm_kernel<2, 1><<<dim3(B_ * NE_ / 128, 4), 256, 0, stream>>>(
        nullptr, 0, Wp_rel, 32, id1, id2, img_f_bf,
        b_rel, nullptr, nullptr, nullptr, nullptr, nullptr,
        edge_keys, nullptr, nullptr, 0, 0);

    // --- fused keys@Wk + tanh-attention score partials ---
    mfma_gemm_kernel<0, 2><<<dim3(B_ * NN_ / 128, 4), 256, 0, stream>>>(
        node_keys, H_, Wp_kn, 16, nullptr, nullptr, nullptr,
        nullptr, nullptr, nullptr, nullptr, qp_n, v_n,
        nullptr, nullptr, sp_n, NN_, B_ * NN_);
    mfma_gemm_kernel<0, 2><<<dim3(B_ * NEK_ / 128, 4), 256, 0, stream>>>(
        edge_keys, H_, Wp_ke, 16, nullptr, nullptr, nullptr,
        nullptr, nullptr, nullptr, nullptr, qp_e, v_e,
        nullptr, nullptr, sp_e, NEK_, B_ * NEK_);

    // --- softmax weights + parallel weighted sums ---
    softmax_w_kernel<<<dim3(B_, 2), 256, 0, stream>>>(sp_n, sp_e, mask_kg, wn, we);
    wsum_kernel<16><<<dim3(B_, 16), 256, 0, stream>>>(wn, node_keys, pn, NN_);
    wsum_kernel<16><<<dim3(B_, 16), 256, 0, stream>>>(we, edge_keys, pe, NEK_);
    fin_reduce_kernel<<<B_ * H_ / 256, 256, 0, stream>>>(pn, pe, fin);

    // --- head ---
    bmatvec_g_kernel<1, 8><<<dim3(B_ / 8, 2), 256, 0, stream>>>(fin, W1, b1, hid, H_, MID_);
    bmatvec_g_kernel<0, 8><<<dim3(B_ / 8, 12), 256, 0, stream>>>(hid, W2, b2, out, MID_, C_);
}

// Round 4
// 512.433 us; speedup vs baseline: 1.9852x; 1.9852x over previous
//
#include <hip/hip_runtime.h>
#include <hip/hip_bf16.h>
#include <math.h>

// Problem dims
#define B_   32
#define NO_  100
#define NE_  600
#define NK_  1000
#define KE_  1000
#define L_   8
#define R_   8
#define H_   512
#define IMG_ 2048
#define LOC_ 5
#define EMB_ 300
#define MID_ 512
#define C_   3000
#define PAD_ 1

#define NN_  (NO_ + NK_)   // 1100 node keys
#define NEK_ (NE_ + KE_)   // 1600 edge keys

typedef __attribute__((ext_vector_type(8))) short bf16x8;
typedef __attribute__((ext_vector_type(4))) float f32x4;

__device__ __forceinline__ float4 ldf4(const float* p) { return *(const float4*)p; }

__device__ __forceinline__ float bf2f(short s) {
    unsigned u = ((unsigned)(unsigned short)s) << 16;
    float f; __builtin_memcpy(&f, &u, 4); return f;
}
__device__ __forceinline__ short f2bf(float f) {
    unsigned u; __builtin_memcpy(&u, &f, 4);
    u = (u + 0x7fffu + ((u >> 16) & 1u)) >> 16;   // round-nearest-even
    return (short)u;
}

// ---------------------------------------------------------------------------
// W_prep: f32 W[K][512] -> bf16 tiles [NB=4][KS][4 kg][128 nl][8 j]
// entry = W[ks*32+kg*8+j][nb*128+nl]  (zeros for k >= K)
__global__ __launch_bounds__(256) void wprep_kernel(
    const float* __restrict__ W, short* __restrict__ Wp, int K, int KS)
{
    int idx = blockIdx.x * 256 + threadIdx.x;
    int total = 4 * KS * 4 * 128;
    if (idx >= total) return;
    int nl = idx & 127;
    int kg = (idx >> 7) & 3;
    int t  = idx >> 9;            // nb*KS + ks
    int ks = t % KS;
    int nb = t / KS;
    int n = nb * 128 + nl;
    short o[8];
#pragma unroll
    for (int j = 0; j < 8; ++j) {
        int k = ks * 32 + kg * 8 + j;
        o[j] = (k < K) ? f2bf(W[(long)k * H_ + n]) : (short)0;
    }
    *(uint4*)&Wp[(long)idx * 8] = *(uint4*)o;
}

// f32 -> bf16 elementwise (n multiple of 8)
__global__ __launch_bounds__(256) void cvt_bf16_kernel(
    const float* __restrict__ src, short* __restrict__ dst, long n)
{
    long i = ((long)blockIdx.x * 256 + threadIdx.x) * 8;
    if (i >= n) return;
    float4 a = ldf4(src + i), b = ldf4(src + i + 4);
    short o[8] = { f2bf(a.x), f2bf(a.y), f2bf(a.z), f2bf(a.w),
                   f2bf(b.x), f2bf(b.y), f2bf(b.z), f2bf(b.w) };
    *(uint4*)&dst[i] = *(uint4*)o;
}

// ---------------------------------------------------------------------------
// MFMA GEMM: 128x128 tile, BK=32, 4 waves each owning 64x64.
// A: bf16 row-major (AV=0) or gathered img_f rows (AV=2, K=1024 two halves).
// B: W_prep tiles (linear copy to LDS).
// EP: 0 img_node (img_f + node_keys w/ loc), 1 img_edge, 2 score partials.
template<int AV, int EP>
__global__ __launch_bounds__(256) void mfma_gemm_kernel(
    const short* __restrict__ A, int lda, const short* __restrict__ Wp, int KS,
    const int* __restrict__ id1, const int* __restrict__ id2,
    const short* __restrict__ Agather,
    const float* __restrict__ bias, const float* __restrict__ bias2,
    const float* __restrict__ loc, const float* __restrict__ Wloc,
    const float* __restrict__ qp, const float* __restrict__ vvec,
    short* __restrict__ out0, short* __restrict__ out1,
    float* __restrict__ sout, int Nrows, int Mtot)
{
    __shared__ __align__(16) short As[4096];   // [4 kg][128 r][8]
    __shared__ __align__(16) short Bs[4096];   // [4 kg][128 n][8]
    int tid = threadIdx.x;
    int m0 = blockIdx.x * 128, nb = blockIdx.y, n0 = nb * 128;
    int w = tid >> 6, l = tid & 63, wr = w >> 1, wc = w & 1;
    int sr = tid >> 1, sh = tid & 1;

    long arow_off = 0; int r1 = 0, r2 = 0;
    if (AV == 0) {
        arow_off = (long)(m0 + sr) * lda;
    } else {
        int i = m0 + sr;
        int b = i / NE_;
        r1 = b * NO_ + id1[i];
        r2 = b * NO_ + id2[i];
    }
    const short* wslab = Wp + (long)nb * KS * 4096;

    uint4 av0, av1, bv0, bv1;
    auto loadA = [&](int ks) {
        const short* p;
        if (AV == 0) p = A + arow_off + ks * 32 + sh * 16;
        else {
            int kk = ks * 32;
            int row = (kk < 512) ? r1 : r2;
            p = Agather + (long)row * 512 + (kk & 511) + sh * 16;
        }
        av0 = *(const uint4*)p;
        av1 = *(const uint4*)(p + 8);
    };
    auto loadB = [&](int ks) {
        const uint4* p = (const uint4*)(wslab + (long)ks * 4096 + tid * 16);
        bv0 = p[0]; bv1 = p[1];
    };

    f32x4 acc[4][4];
#pragma unroll
    for (int m = 0; m < 4; ++m)
#pragma unroll
        for (int n = 0; n < 4; ++n)
#pragma unroll
            for (int k = 0; k < 4; ++k) acc[m][n][k] = 0.f;

    int kg = l >> 4, li = l & 15;
    loadA(0); loadB(0);
    for (int ks = 0; ks < KS; ++ks) {
        __syncthreads();                       // prior reads done
        *(uint4*)&As[(sh * 2) * 1024 + sr * 8]     = av0;
        *(uint4*)&As[(sh * 2 + 1) * 1024 + sr * 8] = av1;
        *(uint4*)&Bs[tid * 16]     = bv0;
        *(uint4*)&Bs[tid * 16 + 8] = bv1;
        __syncthreads();
        if (ks + 1 < KS) { loadA(ks + 1); loadB(ks + 1); }  // prefetch under MFMA
        bf16x8 af[4], bfr[4];
#pragma unroll
        for (int m = 0; m < 4; ++m)
            af[m] = *(const bf16x8*)&As[kg * 1024 + (wr * 64 + m * 16 + li) * 8];
#pragma unroll
        for (int n = 0; n < 4; ++n)
            bfr[n] = *(const bf16x8*)&Bs[kg * 1024 + (wc * 64 + n * 16 + li) * 8];
#pragma unroll
        for (int m = 0; m < 4; ++m)
#pragma unroll
            for (int n = 0; n < 4; ++n)
                acc[m][n] = __builtin_amdgcn_mfma_f32_16x16x32_bf16(af[m], bfr[n], acc[m][n], 0, 0, 0);
    }

    int jrow4 = (l >> 4) * 4;
    if (EP == 0) {                             // img_node
        float bi[4], bl[4], wl[4][5];
#pragma unroll
        for (int n = 0; n < 4; ++n) {
            int col = n0 + wc * 64 + n * 16 + li;
            bi[n] = bias[col]; bl[n] = bias2[col];
#pragma unroll
            for (int j5 = 0; j5 < 5; ++j5) wl[n][j5] = Wloc[j5 * H_ + col];
        }
#pragma unroll
        for (int m = 0; m < 4; ++m)
#pragma unroll
            for (int j = 0; j < 4; ++j) {
                int row = m0 + wr * 64 + m * 16 + jrow4 + j;
                int b = row / NO_, o = row - b * NO_;
                float lv[5];
#pragma unroll
                for (int j5 = 0; j5 < 5; ++j5) lv[j5] = loc[(long)row * 5 + j5];
#pragma unroll
                for (int n = 0; n < 4; ++n) {
                    int col = n0 + wc * 64 + n * 16 + li;
                    float val = acc[m][n][j] + bi[n];
                    out0[(long)row * H_ + col] = f2bf(val);
                    float nk = val + bl[n];
#pragma unroll
                    for (int j5 = 0; j5 < 5; ++j5) nk = fmaf(lv[j5], wl[n][j5], nk);
                    out1[((long)b * NN_ + o) * H_ + col] = f2bf(nk);
                }
            }
    } else if (EP == 1) {                      // img_edge
        float bi[4];
#pragma unroll
        for (int n = 0; n < 4; ++n) bi[n] = bias[n0 + wc * 64 + n * 16 + li];
#pragma unroll
        for (int m = 0; m < 4; ++m)
#pragma unroll
            for (int j = 0; j < 4; ++j) {
                int row = m0 + wr * 64 + m * 16 + jrow4 + j;
                int b = row / NE_, e = row - b * NE_;
#pragma unroll
                for (int n = 0; n < 4; ++n) {
                    int col = n0 + wc * 64 + n * 16 + li;
                    out0[((long)b * NEK_ + e) * H_ + col] = f2bf(acc[m][n][j] + bi[n]);
                }
            }
    } else {                                   // score partials
        float vv[4];
        int cols[4];
#pragma unroll
        for (int n = 0; n < 4; ++n) {
            cols[n] = n0 + wc * 64 + n * 16 + li;
            vv[n] = vvec[cols[n]];
        }
        int slot = nb * 2 + wc;
#pragma unroll
        for (int m = 0; m < 4; ++m)
#pragma unroll
            for (int j = 0; j < 4; ++j) {
                int row = m0 + wr * 64 + m * 16 + jrow4 + j;
                int b = row / Nrows;
                const float* qpb = qp + (long)b * H_;
                float p = 0.f;
#pragma unroll
                for (int n = 0; n < 4; ++n)
                    p += tanhf(qpb[cols[n]] + acc[m][n][j]) * vv[n];
                p += __shfl_xor(p, 1); p += __shfl_xor(p, 2);
                p += __shfl_xor(p, 4); p += __shfl_xor(p, 8);
                if (li == 0) sout[(long)slot * Mtot + row] = p;
            }
    }
}

// ---------------------------------------------------------------------------
// lang_encode with MFMA: 32 rows/block; pooled bf16 in LDS [40 kg][32 r][8];
// W_lang prep [4 nb][10 ks][4096]; 4 waves each own 128 cols.
template<int OUTF32>
__global__ __launch_bounds__(256) void lang_mfma_kernel(
    const int* __restrict__ tokens, int tok_stride, int tok_off,
    const float* __restrict__ embed, const short* __restrict__ Wp,
    const float* __restrict__ bias,
    void* __restrict__ out, int rows_per_b, long out_bstride, long out_roff,
    float* __restrict__ maskout, int nrows)
{
    __shared__ int   toks[32][8];
    __shared__ float rinv[32];
    __shared__ __align__(16) short Ap[40 * 32 * 8];   // 20 KB
    __shared__ __align__(16) short Bs[4 * 4096];      // 32 KB
    int tid = threadIdx.x;
    int base = blockIdx.x * 32;
    {
        int r = tid >> 3, tt = tid & 7;
        toks[r][tt] = tokens[tok_off + (long)(base + r) * tok_stride + tt];
    }
    __syncthreads();
    if (tid < 32) {
        int c = 0;
#pragma unroll
        for (int t = 0; t < 8; ++t) c += (toks[tid][t] != PAD_);
        rinv[tid] = 1.f / fmaxf((float)c, 1.f);
        if (maskout) maskout[base + tid] = (c > 0) ? 1.f : 0.f;
    }
    __syncthreads();

    for (int task = tid; task < 1280; task += 256) {
        int r = task / 40, kg = task - r * 40;
        float s[8] = {0.f,0.f,0.f,0.f,0.f,0.f,0.f,0.f};
        if (kg <= 37) {
#pragma unroll
            for (int t = 0; t < 8; ++t) {
                int tok = toks[r][t];
                if (tok != PAD_) {
                    const float* ep = embed + (long)tok * EMB_ + kg * 8;
                    float4 a = ldf4(ep);
                    s[0] += a.x; s[1] += a.y; s[2] += a.z; s[3] += a.w;
                    if (kg < 37) {
                        float4 b = ldf4(ep + 4);
                        s[4] += b.x; s[5] += b.y; s[6] += b.z; s[7] += b.w;
                    }
                }
            }
        }
        float iv = rinv[r];
        short o[8];
#pragma unroll
        for (int j = 0; j < 8; ++j) o[j] = f2bf(s[j] * iv);
        *(uint4*)&Ap[(kg * 32 + r) * 8] = *(uint4*)o;
    }

    int w = tid >> 6, l = tid & 63, kg = l >> 4, li = l & 15;
    f32x4 acc[2][8];
#pragma unroll
    for (int m = 0; m < 2; ++m)
#pragma unroll
        for (int n = 0; n < 8; ++n)
#pragma unroll
            for (int k = 0; k < 4; ++k) acc[m][n][k] = 0.f;

    for (int ks = 0; ks < 10; ++ks) {
        __syncthreads();
#pragma unroll
        for (int c = 0; c < 4; ++c) {
            int flat = c * 256 + tid;       // 1024 x 32B
            int nb = flat >> 8, rest = flat & 255;
            const uint4* p = (const uint4*)(Wp + (long)(nb * 10 + ks) * 4096 + rest * 16);
            uint4* q = (uint4*)&Bs[nb * 4096 + rest * 16];
            q[0] = p[0]; q[1] = p[1];
        }
        __syncthreads();
        bf16x8 af[2];
#pragma unroll
        for (int m = 0; m < 2; ++m)
            af[m] = *(const bf16x8*)&Ap[((ks * 4 + kg) * 32 + m * 16 + li) * 8];
#pragma unroll
        for (int n = 0; n < 8; ++n) {
            bf16x8 bf = *(const bf16x8*)&Bs[w * 4096 + kg * 1024 + (n * 16 + li) * 8];
#pragma unroll
            for (int m = 0; m < 2; ++m)
                acc[m][n] = __builtin_amdgcn_mfma_f32_16x16x32_bf16(af[m], bf, acc[m][n], 0, 0, 0);
        }
    }

#pragma unroll
    for (int m = 0; m < 2; ++m)
#pragma unroll
        for (int j = 0; j < 4; ++j) {
            int r = m * 16 + (l >> 4) * 4 + j;
            int i = base + r;
            if (i >= nrows) continue;
            int b = i / rows_per_b, k = i - b * rows_per_b;
#pragma unroll
            for (int n = 0; n < 8; ++n) {
                int col = w * 128 + n * 16 + li;
                float val = tanhf(acc[m][n][j] + bias[col]);
                long idx = (long)b * out_bstride + out_roff + (long)k * H_ + col;
                if (OUTF32) ((float*)out)[idx] = val;
                else        ((short*)out)[idx] = f2bf(val);
            }
        }
}

// ---------------------------------------------------------------------------
// Softmax weights: combine 8 deterministic partials, mask, softmax-normalize.
// grid (B, 2): y==0 node set, y==1 edge set.
__global__ __launch_bounds__(256) void softmax_w_kernel(
    const float* __restrict__ sp_n, const float* __restrict__ sp_e,
    const float* __restrict__ maskbuf, float* __restrict__ wn, float* __restrict__ we)
{
    __shared__ float sw[NEK_];
    __shared__ float red[256];
    int b = blockIdx.x, tid = threadIdx.x, set = blockIdx.y;
    const float* sp = set ? sp_e : sp_n;
    float* wout = set ? we : wn;
    int N = set ? NEK_ : NN_;
    long Mtot = set ? (long)B_ * NEK_ : (long)B_ * NN_;

    float lmax = -3.0e38f;
    for (int n = tid; n < N; n += 256) {
        long row = (long)b * N + n;
        float x = 0.f;
#pragma unroll
        for (int s = 0; s < 8; ++s) x += sp[(long)s * Mtot + row];
        if (!set && n >= NO_ && maskbuf[(long)b * NK_ + (n - NO_)] == 0.f) x = -1e30f;
        sw[n] = x;
        lmax = fmaxf(lmax, x);
    }
    red[tid] = lmax; __syncthreads();
    for (int st = 128; st > 0; st >>= 1) {
        if (tid < st) red[tid] = fmaxf(red[tid], red[tid + st]);
        __syncthreads();
    }
    float mx = red[0]; __syncthreads();

    float lsum = 0.f;
    for (int n = tid; n < N; n += 256) {
        float e = expf(sw[n] - mx);
        sw[n] = e;
        lsum += e;
    }
    red[tid] = lsum; __syncthreads();
    for (int st = 128; st > 0; st >>= 1) {
        if (tid < st) red[tid] += red[tid + st];
        __syncthreads();
    }
    float invZ = 1.0f / red[0];
    __syncthreads();
    for (int n = tid; n < N; n += 256)
        wout[(long)b * N + n] = sw[n] * invZ;
}

// ---------------------------------------------------------------------------
// Weighted key sum, split over n: grid (B, SP). Thread: 8 cols x N/SP/4 rows.
// Deterministic partials [SP][B][512].
template<int SP>
__global__ __launch_bounds__(256) void wsum_kernel(
    const float* __restrict__ w, const short* __restrict__ keys,
    float* __restrict__ partial, int N)
{
    __shared__ float red[4][512];
    int b = blockIdx.x, sp = blockIdx.y, tid = threadIdx.x;
    int c8 = (tid & 63) * 8, rsub = tid >> 6;
    int per = (N + SP - 1) / SP;
    int n0 = sp * per, n1 = min(n0 + per, N);
    float acc[8] = {0.f,0.f,0.f,0.f,0.f,0.f,0.f,0.f};
    for (int n = n0 + rsub; n < n1; n += 4) {
        float wv = w[(long)b * N + n];
        bf16x8 k = *(const bf16x8*)&keys[((long)b * N + n) * H_ + c8];
#pragma unroll
        for (int j = 0; j < 8; ++j) acc[j] = fmaf(wv, bf2f(k[j]), acc[j]);
    }
    *(float4*)&red[rsub][c8]     = *(float4*)acc;
    *(float4*)&red[rsub][c8 + 4] = *(float4*)(acc + 4);
    __syncthreads();
    if (rsub == 0) {
        float o[8];
#pragma unroll
        for (int j = 0; j < 8; ++j)
            o[j] = red[0][c8 + j] + red[1][c8 + j] + red[2][c8 + j] + red[3][c8 + j];
        float* op = &partial[((long)sp * B_ + b) * H_ + c8];
        *(float4*)op       = *(float4*)o;
        *(float4*)(op + 4) = *(float4*)(o + 4);
    }
}

// fin = sum over 16 node partials + 16 edge partials. grid (B*H/256).
__global__ __launch_bounds__(256) void fin_reduce_kernel(
    const float* __restrict__ pn, const float* __restrict__ pe, float* __restrict__ fin)
{
    int i = blockIdx.x * 256 + threadIdx.x;
    float s = 0.f;
#pragma unroll
    for (int sp = 0; sp < 16; ++sp)
        s += pn[(long)sp * B_ * H_ + i] + pe[(long)sp * B_ * H_ + i];
    fin[i] = s;
}

// ---------------------------------------------------------------------------
// K-split matvec over all 32 batch rows: grid (ceil(C/256), E/CHUNK, nsets).
// Each block: cols [bx*256,+256), k-slice [by*CHUNK,+CHUNK), all 32 batches.
// Writes deterministic partials p[ks][b][c]; kreduce sums + bias + act.
template<int E, int CHUNK>
__global__ __launch_bounds__(256) void kmatvec_kernel(
    const float* __restrict__ in, const float* __restrict__ Wa,
    const float* __restrict__ Wb, float* __restrict__ pa,
    float* __restrict__ pb, int C)
{
    __shared__ float ins[32 * CHUNK];
    int tid = threadIdx.x;
    int ks = blockIdx.y, k0 = ks * CHUNK;
    const float* W   = (blockIdx.z == 0) ? Wa : Wb;
    float* partial   = (blockIdx.z == 0) ? pa : pb;
    for (int t = tid; t < 32 * CHUNK; t += 256) {
        int b = t / CHUNK, k = t - b * CHUNK;
        ins[t] = in[(long)b * E + k0 + k];
    }
    __syncthreads();
    int c = blockIdx.x * 256 + tid;
    if (c >= C) return;
    float acc[32];
#pragma unroll
    for (int b = 0; b < 32; ++b) acc[b] = 0.f;
    for (int k = 0; k < CHUNK; ++k) {
        float wv = W[(long)(k0 + k) * C + c];
#pragma unroll
        for (int b = 0; b < 32; ++b)
            acc[b] = fmaf(ins[b * CHUNK + k], wv, acc[b]);
    }
#pragma unroll
    for (int b = 0; b < 32; ++b)
        partial[((long)ks * 32 + b) * C + c] = acc[b];
}

// out[b,c] = act(bias[c] + sum_ks p[ks][b][c]); grid (ceil(32*C/256), nsets)
template<int ACT, int KS>
__global__ __launch_bounds__(256) void kreduce_kernel(
    const float* __restrict__ pa, const float* __restrict__ pb,
    const float* __restrict__ biasa, const float* __restrict__ biasb,
    float* __restrict__ oa, float* __restrict__ ob, int C)
{
    int set = blockIdx.y;
    const float* p    = set ? pb : pa;
    const float* bias = set ? biasb : biasa;
    float* o          = set ? ob : oa;
    long i = (long)blockIdx.x * 256 + threadIdx.x;   // over 32*C
    if (i >= 32L * C) return;
    int c = (int)(i % C);
    float s = bias ? bias[c] : 0.f;
#pragma unroll
    for (int ks = 0; ks < KS; ++ks) s += p[(long)ks * 32 * C + i];
    o[i] = (ACT == 1) ? tanhf(s) : s;
}

// ---------------------------------------------------------------------------
extern "C" void kernel_launch(void* const* d_in, const int* in_sizes, int n_in,
                              void* d_out, int out_size, void* d_ws, size_t ws_size,
                              hipStream_t stream)
{
    (void)in_sizes; (void)n_in; (void)out_size; (void)ws_size;

    const float* img_feat  = (const float*)d_in[0];
    const float* img_loc   = (const float*)d_in[1];
    const int*   id1       = (const int*)d_in[2];
    const int*   id2       = (const int*)d_in[3];
    const int*   kg_entity = (const int*)d_in[4];
    const int*   kg_edge   = (const int*)d_in[7];
    const int*   r_nodes   = (const int*)d_in[8];
    const float* embed     = (const float*)d_in[11];
    const float* W_lang    = (const float*)d_in[12];
    const float* b_lang    = (const float*)d_in[13];
    const float* W_img     = (const float*)d_in[14];
    const float* b_img     = (const float*)d_in[15];
    const float* W_loc     = (const float*)d_in[16];
    const float* b_loc     = (const float*)d_in[17];
    const float* W_rel     = (const float*)d_in[18];
    const float* b_rel     = (const float*)d_in[19];
    const float* Wq_n      = (const float*)d_in[20];
    const float* Wk_n      = (const float*)d_in[21];
    const float* v_n       = (const float*)d_in[22];
    const float* Wq_e      = (const float*)d_in[23];
    const float* Wk_e      = (const float*)d_in[24];
    const float* v_e       = (const float*)d_in[25];
    const float* W1        = (const float*)d_in[26];
    const float* b1        = (const float*)d_in[27];
    const float* W2        = (const float*)d_in[28];
    const float* b2        = (const float*)d_in[29];
    float* out = (float*)d_out;

    char* ws = (char*)d_ws;
    size_t off = 0;
    auto allocS = [&](size_t n) { short* p = (short*)(ws + off); off += ((n * 2 + 255) & ~255ULL); return p; };
    auto allocF = [&](size_t n) { float* p = (float*)(ws + off); off += ((n * 4 + 255) & ~255ULL); return p; };

    short* img_feat_bf = allocS((size_t)B_ * NO_ * IMG_);      // 13 MB
    short* Wp_img      = allocS((size_t)4 * 64 * 4096);
    short* Wp_rel      = allocS((size_t)4 * 32 * 4096);
    short* Wp_kn       = allocS((size_t)4 * 16 * 4096);
    short* Wp_ke       = allocS((size_t)4 * 16 * 4096);
    short* Wp_lang     = allocS((size_t)4 * 10 * 4096);
    short* img_f_bf    = allocS((size_t)B_ * NO_ * H_);
    short* node_keys   = allocS((size_t)B_ * NN_ * H_);        // 36 MB
    short* edge_keys   = allocS((size_t)B_ * NEK_ * H_);       // 52 MB
    float* rfeat   = allocF((size_t)B_ * H_);
    float* qp_n    = allocF((size_t)B_ * H_);
    float* qp_e    = allocF((size_t)B_ * H_);
    float* mask_kg = allocF((size_t)B_ * NK_);
    float* sp_n    = allocF((size_t)8 * B_ * NN_);             // score partials
    float* sp_e    = allocF((size_t)8 * B_ * NEK_);
    float* wn      = allocF((size_t)B_ * NN_);                 // softmax weights
    float* we      = allocF((size_t)B_ * NEK_);
    float* pn      = allocF((size_t)16 * B_ * H_);             // wsum partials
    float* pe      = allocF((size_t)16 * B_ * H_);
    float* fin     = allocF((size_t)B_ * H_);
    float* hid     = allocF((size_t)B_ * H_);
    float* pq_n    = allocF((size_t)16 * B_ * MID_);           // kmatvec partials
    float* pq_e    = allocF((size_t)16 * B_ * MID_);
    float* ph1     = allocF((size_t)16 * B_ * MID_);
    float* ph2     = allocF((size_t)16 * B_ * C_);             // 6.1 MB

    // --- weight prep + input conversion ---
    cvt_bf16_kernel<<<(B_ * NO_ * IMG_ / 8 + 255) / 256, 256, 0, stream>>>(
        img_feat, img_feat_bf, (long)B_ * NO_ * IMG_);
    wprep_kernel<<<512, 256, 0, stream>>>(W_img,  Wp_img,  IMG_, 64);
    wprep_kernel<<<256, 256, 0, stream>>>(W_rel,  Wp_rel,  1024, 32);
    wprep_kernel<<<128, 256, 0, stream>>>(Wk_n,   Wp_kn,   512,  16);
    wprep_kernel<<<128, 256, 0, stream>>>(Wk_e,   Wp_ke,   512,  16);
    wprep_kernel<<< 80, 256, 0, stream>>>(W_lang, Wp_lang, EMB_, 10);

    // --- language encodes ---
    lang_mfma_kernel<1><<<1, 256, 0, stream>>>(
        r_nodes, R_ * L_, (R_ - 1) * L_, embed, Wp_lang, b_lang,
        rfeat, 1, (long)H_, 0L, nullptr, B_);
    lang_mfma_kernel<0><<<B_ * NK_ / 32, 256, 0, stream>>>(
        kg_entity, L_, 0, embed, Wp_lang, b_lang,
        node_keys, NK_, (long)NN_ * H_, (long)NO_ * H_, mask_kg, B_ * NK_);
    lang_mfma_kernel<0><<<B_ * KE_ / 32, 256, 0, stream>>>(
        kg_edge, L_, 0, embed, Wp_lang, b_lang,
        edge_keys, KE_, (long)NEK_ * H_, (long)NE_ * H_, nullptr, B_ * KE_);

    // --- qp for root program node (fused pair, K-split) ---
    kmatvec_kernel<H_, 32><<<dim3(2, 16, 2), 256, 0, stream>>>(
        rfeat, Wq_n, Wq_e, pq_n, pq_e, MID_);
    kreduce_kernel<0, 16><<<dim3(B_ * MID_ / 256, 2), 256, 0, stream>>>(
        pq_n, pq_e, nullptr, nullptr, qp_n, qp_e, MID_);

    // --- image branches ---
    mfma_gemm_kernel<0, 0><<<dim3(B_ * NO_ / 128, 4), 256, 0, stream>>>(
        img_feat_bf, IMG_, Wp_img, 64, nullptr, nullptr, nullptr,
        b_img, b_loc, img_loc, W_loc, nullptr, nullptr,
        img_f_bf, node_keys, nullptr, 0, 0);
    mfma_gemm_kernel<2, 1><<<dim3(B_ * NE_ / 128, 4), 256, 0, stream>>>(
        nullptr, 0, Wp_rel, 32, id1, id2, img_f_bf,
        b_rel, nullptr, nullptr, nullptr, nullptr, nullptr,
        edge_keys, nullptr, nullptr, 0, 0);

    // --- fused keys@Wk + tanh-attention score partials ---
    mfma_gemm_kernel<0, 2><<<dim3(B_ * NN_ / 128, 4), 256, 0, stream>>>(
        node_keys, H_, Wp_kn, 16, nullptr, nullptr, nullptr,
        nullptr, nullptr, nullptr, nullptr, qp_n, v_n,
        nullptr, nullptr, sp_n, NN_, B_ * NN_);
    mfma_gemm_kernel<0, 2><<<dim3(B_ * NEK_ / 128, 4), 256, 0, stream>>>(
        edge_keys, H_, Wp_ke, 16, nullptr, nullptr, nullptr,
        nullptr, nullptr, nullptr, nullptr, qp_e, v_e,
        nullptr, nullptr, sp_e, NEK_, B_ * NEK_);

    // --- softmax weights + parallel weighted sums ---
    softmax_w_kernel<<<dim3(B_, 2), 256, 0, stream>>>(sp_n, sp_e, mask_kg, wn, we);
    wsum_kernel<16><<<dim3(B_, 16), 256, 0, stream>>>(wn, node_keys, pn, NN_);
    wsum_kernel<16><<<dim3(B_, 16), 256, 0, stream>>>(we, edge_keys, pe, NEK_);
    fin_reduce_kernel<<<B_ * H_ / 256, 256, 0, stream>>>(pn, pe, fin);

    // --- head: hid = tanh(fin@W1 + b1); out = hid@W2 + b2 ---
    kmatvec_kernel<H_, 32><<<dim3(2, 16, 1), 256, 0, stream>>>(
        fin, W1, W1, ph1, ph1, MID_);
    kreduce_kernel<1, 16><<<dim3(B_ * MID_ / 256, 1), 256, 0, stream>>>(
        ph1, ph1, b1, b1, hid, hid, MID_);
    kmatvec_kernel<MID_, 32><<<dim3((C_ + 255) / 256, 16, 1), 256, 0, stream>>>(
        hid, W2, W2, ph2, ph2, C_);
    kreduce_kernel<0, 16><<<dim3((B_ * C_ + 255) / 256, 1), 256, 0, stream>>>(
        ph2, ph2, b2, b2, out, out, C_);
}

// Round 5
// 447.087 us; speedup vs baseline: 2.2753x; 1.1462x over previous
//
#include <hip/hip_runtime.h>
#include <hip/hip_bf16.h>
#include <math.h>

// Problem dims
#define B_   32
#define NO_  100
#define NE_  600
#define NK_  1000
#define KE_  1000
#define L_   8
#define R_   8
#define H_   512
#define IMG_ 2048
#define LOC_ 5
#define EMB_ 300
#define MID_ 512
#define C_   3000
#define PAD_ 1

#define NN_  (NO_ + NK_)   // 1100 node keys
#define NEK_ (NE_ + KE_)   // 1600 edge keys

typedef __attribute__((ext_vector_type(8))) short bf16x8;
typedef __attribute__((ext_vector_type(4))) float f32x4;

__device__ __forceinline__ float4 ldf4(const float* p) { return *(const float4*)p; }

__device__ __forceinline__ float bf2f(short s) {
    unsigned u = ((unsigned)(unsigned short)s) << 16;
    float f; __builtin_memcpy(&f, &u, 4); return f;
}
__device__ __forceinline__ short f2bf(float f) {
    unsigned u; __builtin_memcpy(&u, &f, 4);
    u = (u + 0x7fffu + ((u >> 16) & 1u)) >> 16;   // round-nearest-even
    return (short)u;
}

// ---------------------------------------------------------------------------
// W_prep: f32 W[K][512] -> bf16 tiles [NB=4][KS][4 kg][128 nl][8 j]
// entry = W[ks*32+kg*8+j][nb*128+nl]  (zeros for k >= K)
__global__ __launch_bounds__(256) void wprep_kernel(
    const float* __restrict__ W, short* __restrict__ Wp, int K, int KS)
{
    int idx = blockIdx.x * 256 + threadIdx.x;
    int total = 4 * KS * 4 * 128;
    if (idx >= total) return;
    int nl = idx & 127;
    int kg = (idx >> 7) & 3;
    int t  = idx >> 9;            // nb*KS + ks
    int ks = t % KS;
    int nb = t / KS;
    int n = nb * 128 + nl;
    short o[8];
#pragma unroll
    for (int j = 0; j < 8; ++j) {
        int k = ks * 32 + kg * 8 + j;
        o[j] = (k < K) ? f2bf(W[(long)k * H_ + n]) : (short)0;
    }
    *(uint4*)&Wp[(long)idx * 8] = *(uint4*)o;
}

// f32 -> bf16 elementwise (n multiple of 8)
__global__ __launch_bounds__(256) void cvt_bf16_kernel(
    const float* __restrict__ src, short* __restrict__ dst, long n)
{
    long i = ((long)blockIdx.x * 256 + threadIdx.x) * 8;
    if (i >= n) return;
    float4 a = ldf4(src + i), b = ldf4(src + i + 4);
    short o[8] = { f2bf(a.x), f2bf(a.y), f2bf(a.z), f2bf(a.w),
                   f2bf(b.x), f2bf(b.y), f2bf(b.z), f2bf(b.w) };
    *(uint4*)&dst[i] = *(uint4*)o;
}

// ---------------------------------------------------------------------------
// Pool: masked mean of bf16 embeddings. 32 rows/block, minimal LDS, high
// occupancy to hide random-gather latency. Writes pooled [row][320] bf16
// (zeros past EMB and for rows >= nrows) + optional "any != PAD" mask.
__global__ __launch_bounds__(256) void pool_kernel(
    const int* __restrict__ tokens, int tok_stride, int tok_off,
    const short* __restrict__ embed_bf, short* __restrict__ pooled,
    float* __restrict__ maskout, int nrows)
{
    __shared__ int   toks[32][8];
    __shared__ float rinv[32];
    int tid = threadIdx.x, base = blockIdx.x * 32;
    {
        int r = tid >> 3, t = tid & 7;
        int i = base + r;
        toks[r][t] = (i < nrows) ? tokens[tok_off + (long)i * tok_stride + t] : PAD_;
    }
    __syncthreads();
    if (tid < 32) {
        int c = 0;
#pragma unroll
        for (int t = 0; t < 8; ++t) c += (toks[tid][t] != PAD_);
        rinv[tid] = 1.0f / fmaxf((float)c, 1.0f);
        int i = base + tid;
        if (maskout && i < nrows) maskout[i] = (c > 0) ? 1.0f : 0.0f;
    }
    __syncthreads();

    for (int task = tid; task < 32 * 40; task += 256) {
        int r = task / 40, kg = task - r * 40;    // row, 8-elem chunk
        float s[8] = {0.f,0.f,0.f,0.f,0.f,0.f,0.f,0.f};
        if (kg < 38) {                            // EMB=300 -> chunks 0..37
#pragma unroll
            for (int t = 0; t < 8; ++t) {
                int tok = toks[r][t];
                if (tok != PAD_) {
                    bf16x8 e = *(const bf16x8*)&embed_bf[(long)tok * EMB_ + kg * 8];
#pragma unroll
                    for (int j = 0; j < 8; ++j) s[j] += bf2f(e[j]);
                }
            }
        }
        float iv = rinv[r];
        short o[8];
#pragma unroll
        for (int j = 0; j < 8; ++j) {
            float v = s[j] * iv;
            if (kg == 37 && j >= 4) v = 0.f;      // elems 300..303 are overread
            o[j] = f2bf(v);
        }
        *(uint4*)&pooled[(long)(base + r) * 320 + kg * 8] = *(uint4*)o;
    }
}

// ---------------------------------------------------------------------------
// Keys GEMM: pooled[rows][320] @ W_lang (KS=10) -> tanh(+bias) -> out.
// 128x128 tile, 4 waves, same core as mfma_gemm_kernel.
template<int OUTF32>
__global__ __launch_bounds__(256) void keys_gemm_kernel(
    const short* __restrict__ A, const short* __restrict__ Wp,
    const float* __restrict__ bias,
    void* __restrict__ out, int rows_per_b, long out_bstride, long out_roff,
    float* __restrict__ unused, int nrows)
{
    const int KS = 10;
    __shared__ __align__(16) short As[4096];
    __shared__ __align__(16) short Bs[4096];
    int tid = threadIdx.x;
    int m0 = blockIdx.x * 128, nb = blockIdx.y, n0 = nb * 128;
    int w = tid >> 6, l = tid & 63, wr = w >> 1, wc = w & 1;
    int sr = tid >> 1, sh = tid & 1;
    long arow_off = (long)(m0 + sr) * 320;
    const short* wslab = Wp + (long)nb * KS * 4096;

    uint4 av0, av1, bv0, bv1;
    auto loadA = [&](int ks) {
        const short* p = A + arow_off + ks * 32 + sh * 16;
        av0 = *(const uint4*)p;
        av1 = *(const uint4*)(p + 8);
    };
    auto loadB = [&](int ks) {
        const uint4* p = (const uint4*)(wslab + (long)ks * 4096 + tid * 16);
        bv0 = p[0]; bv1 = p[1];
    };

    f32x4 acc[4][4];
#pragma unroll
    for (int m = 0; m < 4; ++m)
#pragma unroll
        for (int n = 0; n < 4; ++n)
#pragma unroll
            for (int k = 0; k < 4; ++k) acc[m][n][k] = 0.f;

    int kg = l >> 4, li = l & 15;
    loadA(0); loadB(0);
    for (int ks = 0; ks < KS; ++ks) {
        __syncthreads();
        *(uint4*)&As[(sh * 2) * 1024 + sr * 8]     = av0;
        *(uint4*)&As[(sh * 2 + 1) * 1024 + sr * 8] = av1;
        *(uint4*)&Bs[tid * 16]     = bv0;
        *(uint4*)&Bs[tid * 16 + 8] = bv1;
        __syncthreads();
        if (ks + 1 < KS) { loadA(ks + 1); loadB(ks + 1); }
        bf16x8 af[4], bfr[4];
#pragma unroll
        for (int m = 0; m < 4; ++m)
            af[m] = *(const bf16x8*)&As[kg * 1024 + (wr * 64 + m * 16 + li) * 8];
#pragma unroll
        for (int n = 0; n < 4; ++n)
            bfr[n] = *(const bf16x8*)&Bs[kg * 1024 + (wc * 64 + n * 16 + li) * 8];
#pragma unroll
        for (int m = 0; m < 4; ++m)
#pragma unroll
            for (int n = 0; n < 4; ++n)
                acc[m][n] = __builtin_amdgcn_mfma_f32_16x16x32_bf16(af[m], bfr[n], acc[m][n], 0, 0, 0);
    }

    int jrow4 = (l >> 4) * 4;
    float bv[4];
#pragma unroll
    for (int n = 0; n < 4; ++n) bv[n] = bias[n0 + wc * 64 + n * 16 + li];
#pragma unroll
    for (int m = 0; m < 4; ++m)
#pragma unroll
        for (int j = 0; j < 4; ++j) {
            int i = m0 + wr * 64 + m * 16 + jrow4 + j;
            if (i >= nrows) continue;
            int b = i / rows_per_b, k = i - b * rows_per_b;
#pragma unroll
            for (int n = 0; n < 4; ++n) {
                int col = n0 + wc * 64 + n * 16 + li;
                float val = tanhf(acc[m][n][j] + bv[n]);
                long idx = (long)b * out_bstride + out_roff + (long)k * H_ + col;
                if (OUTF32) ((float*)out)[idx] = val;
                else        ((short*)out)[idx] = f2bf(val);
            }
        }
    (void)unused;
}

// ---------------------------------------------------------------------------
// MFMA GEMM: 128x128 tile, BK=32, 4 waves each owning 64x64.
// A: bf16 row-major (AV=0) or gathered img_f rows (AV=2, K=1024 two halves).
// B: W_prep tiles (linear copy to LDS).
// EP: 0 img_node (img_f + node_keys w/ loc), 1 img_edge, 2 score partials.
template<int AV, int EP>
__global__ __launch_bounds__(256) void mfma_gemm_kernel(
    const short* __restrict__ A, int lda, const short* __restrict__ Wp, int KS,
    const int* __restrict__ id1, const int* __restrict__ id2,
    const short* __restrict__ Agather,
    const float* __restrict__ bias, const float* __restrict__ bias2,
    const float* __restrict__ loc, const float* __restrict__ Wloc,
    const float* __restrict__ qp, const float* __restrict__ vvec,
    short* __restrict__ out0, short* __restrict__ out1,
    float* __restrict__ sout, int Nrows, int Mtot)
{
    __shared__ __align__(16) short As[4096];   // [4 kg][128 r][8]
    __shared__ __align__(16) short Bs[4096];   // [4 kg][128 n][8]
    int tid = threadIdx.x;
    int m0 = blockIdx.x * 128, nb = blockIdx.y, n0 = nb * 128;
    int w = tid >> 6, l = tid & 63, wr = w >> 1, wc = w & 1;
    int sr = tid >> 1, sh = tid & 1;

    long arow_off = 0; int r1 = 0, r2 = 0;
    if (AV == 0) {
        arow_off = (long)(m0 + sr) * lda;
    } else {
        int i = m0 + sr;
        int b = i / NE_;
        r1 = b * NO_ + id1[i];
        r2 = b * NO_ + id2[i];
    }
    const short* wslab = Wp + (long)nb * KS * 4096;

    uint4 av0, av1, bv0, bv1;
    auto loadA = [&](int ks) {
        const short* p;
        if (AV == 0) p = A + arow_off + ks * 32 + sh * 16;
        else {
            int kk = ks * 32;
            int row = (kk < 512) ? r1 : r2;
            p = Agather + (long)row * 512 + (kk & 511) + sh * 16;
        }
        av0 = *(const uint4*)p;
        av1 = *(const uint4*)(p + 8);
    };
    auto loadB = [&](int ks) {
        const uint4* p = (const uint4*)(wslab + (long)ks * 4096 + tid * 16);
        bv0 = p[0]; bv1 = p[1];
    };

    f32x4 acc[4][4];
#pragma unroll
    for (int m = 0; m < 4; ++m)
#pragma unroll
        for (int n = 0; n < 4; ++n)
#pragma unroll
            for (int k = 0; k < 4; ++k) acc[m][n][k] = 0.f;

    int kg = l >> 4, li = l & 15;
    loadA(0); loadB(0);
    for (int ks = 0; ks < KS; ++ks) {
        __syncthreads();                       // prior reads done
        *(uint4*)&As[(sh * 2) * 1024 + sr * 8]     = av0;
        *(uint4*)&As[(sh * 2 + 1) * 1024 + sr * 8] = av1;
        *(uint4*)&Bs[tid * 16]     = bv0;
        *(uint4*)&Bs[tid * 16 + 8] = bv1;
        __syncthreads();
        if (ks + 1 < KS) { loadA(ks + 1); loadB(ks + 1); }  // prefetch under MFMA
        bf16x8 af[4], bfr[4];
#pragma unroll
        for (int m = 0; m < 4; ++m)
            af[m] = *(const bf16x8*)&As[kg * 1024 + (wr * 64 + m * 16 + li) * 8];
#pragma unroll
        for (int n = 0; n < 4; ++n)
            bfr[n] = *(const bf16x8*)&Bs[kg * 1024 + (wc * 64 + n * 16 + li) * 8];
#pragma unroll
        for (int m = 0; m < 4; ++m)
#pragma unroll
            for (int n = 0; n < 4; ++n)
                acc[m][n] = __builtin_amdgcn_mfma_f32_16x16x32_bf16(af[m], bfr[n], acc[m][n], 0, 0, 0);
    }

    int jrow4 = (l >> 4) * 4;
    if (EP == 0) {                             // img_node
        float bi[4], bl[4], wl[4][5];
#pragma unroll
        for (int n = 0; n < 4; ++n) {
            int col = n0 + wc * 64 + n * 16 + li;
            bi[n] = bias[col]; bl[n] = bias2[col];
#pragma unroll
            for (int j5 = 0; j5 < 5; ++j5) wl[n][j5] = Wloc[j5 * H_ + col];
        }
#pragma unroll
        for (int m = 0; m < 4; ++m)
#pragma unroll
            for (int j = 0; j < 4; ++j) {
                int row = m0 + wr * 64 + m * 16 + jrow4 + j;
                int b = row / NO_, o = row - b * NO_;
                float lv[5];
#pragma unroll
                for (int j5 = 0; j5 < 5; ++j5) lv[j5] = loc[(long)row * 5 + j5];
#pragma unroll
                for (int n = 0; n < 4; ++n) {
                    int col = n0 + wc * 64 + n * 16 + li;
                    float val = acc[m][n][j] + bi[n];
                    out0[(long)row * H_ + col] = f2bf(val);
                    float nk = val + bl[n];
#pragma unroll
                    for (int j5 = 0; j5 < 5; ++j5) nk = fmaf(lv[j5], wl[n][j5], nk);
                    out1[((long)b * NN_ + o) * H_ + col] = f2bf(nk);
                }
            }
    } else if (EP == 1) {                      // img_edge
        float bi[4];
#pragma unroll
        for (int n = 0; n < 4; ++n) bi[n] = bias[n0 + wc * 64 + n * 16 + li];
#pragma unroll
        for (int m = 0; m < 4; ++m)
#pragma unroll
            for (int j = 0; j < 4; ++j) {
                int row = m0 + wr * 64 + m * 16 + jrow4 + j;
                int b = row / NE_, e = row - b * NE_;
#pragma unroll
                for (int n = 0; n < 4; ++n) {
                    int col = n0 + wc * 64 + n * 16 + li;
                    out0[((long)b * NEK_ + e) * H_ + col] = f2bf(acc[m][n][j] + bi[n]);
                }
            }
    } else {                                   // score partials
        float vv[4];
        int cols[4];
#pragma unroll
        for (int n = 0; n < 4; ++n) {
            cols[n] = n0 + wc * 64 + n * 16 + li;
            vv[n] = vvec[cols[n]];
        }
        int slot = nb * 2 + wc;
#pragma unroll
        for (int m = 0; m < 4; ++m)
#pragma unroll
            for (int j = 0; j < 4; ++j) {
                int row = m0 + wr * 64 + m * 16 + jrow4 + j;
                int b = row / Nrows;
                const float* qpb = qp + (long)b * H_;
                float p = 0.f;
#pragma unroll
                for (int n = 0; n < 4; ++n)
                    p += tanhf(qpb[cols[n]] + acc[m][n][j]) * vv[n];
                p += __shfl_xor(p, 1); p += __shfl_xor(p, 2);
                p += __shfl_xor(p, 4); p += __shfl_xor(p, 8);
                if (li == 0) sout[(long)slot * Mtot + row] = p;
            }
    }
}

// ---------------------------------------------------------------------------
// Softmax weights: combine 8 deterministic partials, mask, softmax-normalize.
// grid (B, 2): y==0 node set, y==1 edge set.
__global__ __launch_bounds__(256) void softmax_w_kernel(
    const float* __restrict__ sp_n, const float* __restrict__ sp_e,
    const float* __restrict__ maskbuf, float* __restrict__ wn, float* __restrict__ we)
{
    __shared__ float sw[NEK_];
    __shared__ float red[256];
    int b = blockIdx.x, tid = threadIdx.x, set = blockIdx.y;
    const float* sp = set ? sp_e : sp_n;
    float* wout = set ? we : wn;
    int N = set ? NEK_ : NN_;
    long Mtot = set ? (long)B_ * NEK_ : (long)B_ * NN_;

    float lmax = -3.0e38f;
    for (int n = tid; n < N; n += 256) {
        long row = (long)b * N + n;
        float x = 0.f;
#pragma unroll
        for (int s = 0; s < 8; ++s) x += sp[(long)s * Mtot + row];
        if (!set && n >= NO_ && maskbuf[(long)b * NK_ + (n - NO_)] == 0.f) x = -1e30f;
        sw[n] = x;
        lmax = fmaxf(lmax, x);
    }
    red[tid] = lmax; __syncthreads();
    for (int st = 128; st > 0; st >>= 1) {
        if (tid < st) red[tid] = fmaxf(red[tid], red[tid + st]);
        __syncthreads();
    }
    float mx = red[0]; __syncthreads();

    float lsum = 0.f;
    for (int n = tid; n < N; n += 256) {
        float e = expf(sw[n] - mx);
        sw[n] = e;
        lsum += e;
    }
    red[tid] = lsum; __syncthreads();
    for (int st = 128; st > 0; st >>= 1) {
        if (tid < st) red[tid] += red[tid + st];
        __syncthreads();
    }
    float invZ = 1.0f / red[0];
    __syncthreads();
    for (int n = tid; n < N; n += 256)
        wout[(long)b * N + n] = sw[n] * invZ;
}

// ---------------------------------------------------------------------------
// Weighted key sum, split over n: grid (B, SP). Thread: 8 cols x N/SP/4 rows.
// Deterministic partials [SP][B][512].
template<int SP>
__global__ __launch_bounds__(256) void wsum_kernel(
    const float* __restrict__ w, const short* __restrict__ keys,
    float* __restrict__ partial, int N)
{
    __shared__ float red[4][512];
    int b = blockIdx.x, sp = blockIdx.y, tid = threadIdx.x;
    int c8 = (tid & 63) * 8, rsub = tid >> 6;
    int per = (N + SP - 1) / SP;
    int n0 = sp * per, n1 = min(n0 + per, N);
    float acc[8] = {0.f,0.f,0.f,0.f,0.f,0.f,0.f,0.f};
    for (int n = n0 + rsub; n < n1; n += 4) {
        float wv = w[(long)b * N + n];
        bf16x8 k = *(const bf16x8*)&keys[((long)b * N + n) * H_ + c8];
#pragma unroll
        for (int j = 0; j < 8; ++j) acc[j] = fmaf(wv, bf2f(k[j]), acc[j]);
    }
    *(float4*)&red[rsub][c8]     = *(float4*)acc;
    *(float4*)&red[rsub][c8 + 4] = *(float4*)(acc + 4);
    __syncthreads();
    if (rsub == 0) {
        float o[8];
#pragma unroll
        for (int j = 0; j < 8; ++j)
            o[j] = red[0][c8 + j] + red[1][c8 + j] + red[2][c8 + j] + red[3][c8 + j];
        float* op = &partial[((long)sp * B_ + b) * H_ + c8];
        *(float4*)op       = *(float4*)o;
        *(float4*)(op + 4) = *(float4*)(o + 4);
    }
}

// fin = sum over 16 node partials + 16 edge partials. grid (B*H/256).
__global__ __launch_bounds__(256) void fin_reduce_kernel(
    const float* __restrict__ pn, const float* __restrict__ pe, float* __restrict__ fin)
{
    int i = blockIdx.x * 256 + threadIdx.x;
    float s = 0.f;
#pragma unroll
    for (int sp = 0; sp < 16; ++sp)
        s += pn[(long)sp * B_ * H_ + i] + pe[(long)sp * B_ * H_ + i];
    fin[i] = s;
}

// ---------------------------------------------------------------------------
// K-split matvec over all 32 batch rows: grid (ceil(C/256), E/CHUNK, nsets).
// Each block: cols [bx*256,+256), k-slice [by*CHUNK,+CHUNK), all 32 batches.
// Writes deterministic partials p[ks][b][c]; kreduce sums + bias + act.
template<int E, int CHUNK>
__global__ __launch_bounds__(256) void kmatvec_kernel(
    const float* __restrict__ in, const float* __restrict__ Wa,
    const float* __restrict__ Wb, float* __restrict__ pa,
    float* __restrict__ pb, int C)
{
    __shared__ float ins[32 * CHUNK];
    int tid = threadIdx.x;
    int ks = blockIdx.y, k0 = ks * CHUNK;
    const float* W   = (blockIdx.z == 0) ? Wa : Wb;
    float* partial   = (blockIdx.z == 0) ? pa : pb;
    for (int t = tid; t < 32 * CHUNK; t += 256) {
        int b = t / CHUNK, k = t - b * CHUNK;
        ins[t] = in[(long)b * E + k0 + k];
    }
    __syncthreads();
    int c = blockIdx.x * 256 + tid;
    if (c >= C) return;
    float acc[32];
#pragma unroll
    for (int b = 0; b < 32; ++b) acc[b] = 0.f;
    for (int k = 0; k < CHUNK; ++k) {
        float wv = W[(long)(k0 + k) * C + c];
#pragma unroll
        for (int b = 0; b < 32; ++b)
            acc[b] = fmaf(ins[b * CHUNK + k], wv, acc[b]);
    }
#pragma unroll
    for (int b = 0; b < 32; ++b)
        partial[((long)ks * 32 + b) * C + c] = acc[b];
}

// out[b,c] = act(bias[c] + sum_ks p[ks][b][c]); grid (ceil(32*C/256), nsets)
template<int ACT, int KS>
__global__ __launch_bounds__(256) void kreduce_kernel(
    const float* __restrict__ pa, const float* __restrict__ pb,
    const float* __restrict__ biasa, const float* __restrict__ biasb,
    float* __restrict__ oa, float* __restrict__ ob, int C)
{
    int set = blockIdx.y;
    const float* p    = set ? pb : pa;
    const float* bias = set ? biasb : biasa;
    float* o          = set ? ob : oa;
    long i = (long)blockIdx.x * 256 + threadIdx.x;   // over 32*C
    if (i >= 32L * C) return;
    int c = (int)(i % C);
    float s = bias ? bias[c] : 0.f;
#pragma unroll
    for (int ks = 0; ks < KS; ++ks) s += p[(long)ks * 32 * C + i];
    o[i] = (ACT == 1) ? tanhf(s) : s;
}

// ---------------------------------------------------------------------------
extern "C" void kernel_launch(void* const* d_in, const int* in_sizes, int n_in,
                              void* d_out, int out_size, void* d_ws, size_t ws_size,
                              hipStream_t stream)
{
    (void)in_sizes; (void)n_in; (void)out_size; (void)ws_size;

    const float* img_feat  = (const float*)d_in[0];
    const float* img_loc   = (const float*)d_in[1];
    const int*   id1       = (const int*)d_in[2];
    const int*   id2       = (const int*)d_in[3];
    const int*   kg_entity = (const int*)d_in[4];
    const int*   kg_edge   = (const int*)d_in[7];
    const int*   r_nodes   = (const int*)d_in[8];
    const float* embed     = (const float*)d_in[11];
    const float* W_lang    = (const float*)d_in[12];
    const float* b_lang    = (const float*)d_in[13];
    const float* W_img     = (const float*)d_in[14];
    const float* b_img     = (const float*)d_in[15];
    const float* W_loc     = (const float*)d_in[16];
    const float* b_loc     = (const float*)d_in[17];
    const float* W_rel     = (const float*)d_in[18];
    const float* b_rel     = (const float*)d_in[19];
    const float* Wq_n      = (const float*)d_in[20];
    const float* Wk_n      = (const float*)d_in[21];
    const float* v_n       = (const float*)d_in[22];
    const float* Wq_e      = (const float*)d_in[23];
    const float* Wk_e      = (const float*)d_in[24];
    const float* v_e       = (const float*)d_in[25];
    const float* W1        = (const float*)d_in[26];
    const float* b1        = (const float*)d_in[27];
    const float* W2        = (const float*)d_in[28];
    const float* b2        = (const float*)d_in[29];
    float* out = (float*)d_out;

    char* ws = (char*)d_ws;
    size_t off = 0;
    auto allocS = [&](size_t n) { short* p = (short*)(ws + off); off += ((n * 2 + 255) & ~255ULL); return p; };
    auto allocF = [&](size_t n) { float* p = (float*)(ws + off); off += ((n * 4 + 255) & ~255ULL); return p; };

    short* img_feat_bf = allocS((size_t)B_ * NO_ * IMG_);      // 13 MB
    short* embed_bf    = allocS((size_t)10000 * EMB_ + 16);    // 6 MB (+tail pad)
    short* Wp_img      = allocS((size_t)4 * 64 * 4096);
    short* Wp_rel      = allocS((size_t)4 * 32 * 4096);
    short* Wp_kn       = allocS((size_t)4 * 16 * 4096);
    short* Wp_ke       = allocS((size_t)4 * 16 * 4096);
    short* Wp_lang     = allocS((size_t)4 * 10 * 4096);
    short* img_f_bf    = allocS((size_t)B_ * NO_ * H_);
    short* node_keys   = allocS((size_t)B_ * NN_ * H_);        // 36 MB
    short* edge_keys   = allocS((size_t)B_ * NEK_ * H_);       // 52 MB
    short* pooled_n    = allocS((size_t)B_ * NK_ * 320);       // 20.5 MB
    short* pooled_e    = allocS((size_t)B_ * KE_ * 320);       // 20.5 MB
    short* pooled_r    = allocS((size_t)128 * 320);
    float* rfeat   = allocF((size_t)B_ * H_);
    float* qp_n    = allocF((size_t)B_ * H_);
    float* qp_e    = allocF((size_t)B_ * H_);
    float* mask_kg = allocF((size_t)B_ * NK_);
    float* sp_n    = allocF((size_t)8 * B_ * NN_);             // score partials
    float* sp_e    = allocF((size_t)8 * B_ * NEK_);
    float* wn      = allocF((size_t)B_ * NN_);                 // softmax weights
    float* we      = allocF((size_t)B_ * NEK_);
    float* pn      = allocF((size_t)16 * B_ * H_);             // wsum partials
    float* pe      = allocF((size_t)16 * B_ * H_);
    float* fin     = allocF((size_t)B_ * H_);
    float* hid     = allocF((size_t)B_ * H_);
    float* pq_n    = allocF((size_t)16 * B_ * MID_);           // kmatvec partials
    float* pq_e    = allocF((size_t)16 * B_ * MID_);
    float* ph1     = allocF((size_t)16 * B_ * MID_);
    float* ph2     = allocF((size_t)16 * B_ * C_);             // 6.1 MB

    // --- weight prep + input conversion ---
    cvt_bf16_kernel<<<(B_ * NO_ * IMG_ / 8 + 255) / 256, 256, 0, stream>>>(
        img_feat, img_feat_bf, (long)B_ * NO_ * IMG_);
    cvt_bf16_kernel<<<(10000 * EMB_ / 8 + 255) / 256, 256, 0, stream>>>(
        embed, embed_bf, (long)10000 * EMB_);
    wprep_kernel<<<512, 256, 0, stream>>>(W_img,  Wp_img,  IMG_, 64);
    wprep_kernel<<<256, 256, 0, stream>>>(W_rel,  Wp_rel,  1024, 32);
    wprep_kernel<<<128, 256, 0, stream>>>(Wk_n,   Wp_kn,   512,  16);
    wprep_kernel<<<128, 256, 0, stream>>>(Wk_e,   Wp_ke,   512,  16);
    wprep_kernel<<< 80, 256, 0, stream>>>(W_lang, Wp_lang, EMB_, 10);

    // --- pooled embeddings (gather phase, high occupancy) ---
    pool_kernel<<<B_ * NK_ / 32, 256, 0, stream>>>(
        kg_entity, L_, 0, embed_bf, pooled_n, mask_kg, B_ * NK_);
    pool_kernel<<<B_ * KE_ / 32, 256, 0, stream>>>(
        kg_edge, L_, 0, embed_bf, pooled_e, nullptr, B_ * KE_);
    pool_kernel<<<4, 256, 0, stream>>>(
        r_nodes, R_ * L_, (R_ - 1) * L_, embed_bf, pooled_r, nullptr, B_);

    // --- lang projections (MFMA GEMM phase) ---
    keys_gemm_kernel<0><<<dim3(B_ * NK_ / 128, 4), 256, 0, stream>>>(
        pooled_n, Wp_lang, b_lang, node_keys, NK_, (long)NN_ * H_, (long)NO_ * H_,
        nullptr, B_ * NK_);
    keys_gemm_kernel<0><<<dim3(B_ * KE_ / 128, 4), 256, 0, stream>>>(
        pooled_e, Wp_lang, b_lang, edge_keys, KE_, (long)NEK_ * H_, (long)NE_ * H_,
        nullptr, B_ * KE_);
    keys_gemm_kernel<1><<<dim3(1, 4), 256, 0, stream>>>(
        pooled_r, Wp_lang, b_lang, rfeat, 1, (long)H_, 0L, nullptr, B_);

    // --- qp for root program node (fused pair, K-split) ---
    kmatvec_kernel<H_, 32><<<dim3(2, 16, 2), 256, 0, stream>>>(
        rfeat, Wq_n, Wq_e, pq_n, pq_e, MID_);
    kreduce_kernel<0, 16><<<dim3(B_ * MID_ / 256, 2), 256, 0, stream>>>(
        pq_n, pq_e, nullptr, nullptr, qp_n, qp_e, MID_);

    // --- image branches ---
    mfma_gemm_kernel<0, 0><<<dim3(B_ * NO_ / 128, 4), 256, 0, stream>>>(
        img_feat_bf, IMG_, Wp_img, 64, nullptr, nullptr, nullptr,
        b_img, b_loc, img_loc, W_loc, nullptr, nullptr,
        img_f_bf, node_keys, nullptr, 0, 0);
    mfma_gemm_kernel<2, 1><<<dim3(B_ * NE_ / 128, 4), 256, 0, stream>>>(
        nullptr, 0, Wp_rel, 32, id1, id2, img_f_bf,
        b_rel, nullptr, nullptr, nullptr, nullptr, nullptr,
        edge_keys, nullptr, nullptr, 0, 0);

    // --- fused keys@Wk + tanh-attention score partials ---
    mfma_gemm_kernel<0, 2><<<dim3(B_ * NN_ / 128, 4), 256, 0, stream>>>(
        node_keys, H_, Wp_kn, 16, nullptr, nullptr, nullptr,
        nullptr, nullptr, nullptr, nullptr, qp_n, v_n,
        nullptr, nullptr, sp_n, NN_, B_ * NN_);
    mfma_gemm_kernel<0, 2><<<dim3(B_ * NEK_ / 128, 4), 256, 0, stream>>>(
        edge_keys, H_, Wp_ke, 16, nullptr, nullptr, nullptr,
        nullptr, nullptr, nullptr, nullptr, qp_e, v_e,
        nullptr, nullptr, sp_e, NEK_, B_ * NEK_);

    // --- softmax weights + parallel weighted sums ---
    softmax_w_kernel<<<dim3(B_, 2), 256, 0, stream>>>(sp_n, sp_e, mask_kg, wn, we);
    wsum_kernel<16><<<dim3(B_, 16), 256, 0, stream>>>(wn, node_keys, pn, NN_);
    wsum_kernel<16><<<dim3(B_, 16), 256, 0, stream>>>(we, edge_keys, pe, NEK_);
    fin_reduce_kernel<<<B_ * H_ / 256, 256, 0, stream>>>(pn, pe, fin);

    // --- head: hid = tanh(fin@W1 + b1); out = hid@W2 + b2 ---
    kmatvec_kernel<H_, 32><<<dim3(2, 16, 1), 256, 0, stream>>>(
        fin, W1, W1, ph1, ph1, MID_);
    kreduce_kernel<1, 16><<<dim3(B_ * MID_ / 256, 1), 256, 0, stream>>>(
        ph1, ph1, b1, b1, hid, hid, MID_);
    kmatvec_kernel<MID_, 32><<<dim3((C_ + 255) / 256, 16, 1), 256, 0, stream>>>(
        hid, W2, W2, ph2, ph2, C_);
    kreduce_kernel<0, 16><<<dim3((B_ * C_ + 255) / 256, 1), 256, 0, stream>>>(
        ph2, ph2, b2, b2, out, out, C_);
}